// Round 5
// baseline (167.196 us; speedup 1.0000x reference)
//
#include <hip/hip_runtime.h>
#include <hip/hip_bf16.h>

// EF_42511586295882: MPNN potential. N=16384, E=262144, B=512, F=32, K=16.
// Only l=0 of the equivariant features reaches the output (sph_harm dead
// except sh0=0.282095); radial basis = Chebyshev recurrence T_k(t).
// Round-5: fixed-stride per-atom bins (cap 48) replace CSR+scan entirely.
// Active degree ~ Poisson(6.84); P(deg>48) ~ 1e-18 (writes clamped anyway).
//  K1 edge_k   : 4 edges/thread; r<6 filter; cut/tt/ZBL; bins[d*48+slot]
//  K2 gather1_k: wave/atom, 2 records in flight; cut*(T@Wc)[f]*embed[zs,f];
//                fused MLP1 -> x0
//  K3 gather2_k: wave/atom; cut*(T@Wr1_1)[f]*x0[s,f]; fused MLP2 + w_out
//                + b_out + pair -> atomicAdd out[batch]

#define FDIM 32
#define KDIM 16
#define BINCAP 48
#define MAXZ 18   // setup: atomic_numbers in [0,18)

// ---- K1: per-edge geometry + transcendentals + ZBL + bin placement ----
__global__ __launch_bounds__(256) void edge_k(
    const int* __restrict__ dst, const int* __restrict__ src,
    const int* __restrict__ Z, const float* __restrict__ pos,
    int* __restrict__ counts, float* __restrict__ pair,
    int4* __restrict__ bins, int E)
{
    __shared__ float zpow[MAXZ];
    int tid = threadIdx.x;
    if (tid < MAXZ) zpow[tid] = __powf((float)tid, 0.23f);
    __syncthreads();

    int base = (blockIdx.x * 256 + tid) * 4;
    if (base >= E) return;
    // 4 edges per thread via vector index loads
    int4 d4 = *(const int4*)(dst + base);
    int4 s4 = *(const int4*)(src + base);
    #pragma unroll
    for (int j = 0; j < 4; ++j) {
        int i = base + j;
        if (i >= E) break;
        int d = (&d4.x)[j], s = (&s4.x)[j];
        float dx = pos[3 * s]     - pos[3 * d];
        float dy = pos[3 * s + 1] - pos[3 * d + 1];
        float dz = pos[3 * s + 2] - pos[3 * d + 2];
        float r2 = dx * dx + dy * dy + dz * dz;
        if (r2 >= 36.0f) continue;
        float r = fmaxf(sqrtf(r2 + 1e-10f), 1e-4f);
        float u = r * (1.0f / 6.0f);
        float u2 = u * u;
        float cut = __expf(-u2 / (1.0f - u2));
        float tt = fminf(fmaxf(2.0f * __expf(-r) - 1.0f, -1.0f), 1.0f);
        int zs_i = Z[s], zd_i = Z[d];
        // ZBL pair energy
        float zd = (float)zd_i, zsf = (float)zs_i;
        float zsum = zpow[zd_i] + zpow[zs_i] + 1e-10f;
        float ra = r * zsum * (1.0f / 0.46853312f);
        float phi = 0.18175f * __expf(-3.1998f  * ra)
                  + 0.50986f * __expf(-0.94229f * ra)
                  + 0.28022f * __expf(-0.4029f  * ra)
                  + 0.02817f * __expf(-0.20162f * ra);
        atomicAdd(&pair[d], 0.5f * 14.399645f * zd * zsf / r * phi * cut);
        int slot = atomicAdd(&counts[d], 1);
        if (slot < BINCAP)
            bins[d * BINCAP + slot] =
                make_int4(s | (zs_i << 14), 0,
                          __float_as_int(cut), __float_as_int(tt));
    }
}

// ---- K2: gather layer-0 (wave/atom, 2 records in flight) + fused MLP1 ----
__global__ __launch_bounds__(256) void gather1_k(
    const int* __restrict__ counts, const int4* __restrict__ bins,
    const float* __restrict__ embed, const float* __restrict__ Wr1_0,
    const float* __restrict__ Wr2_0, const float* __restrict__ W1_0,
    const float* __restrict__ W2_0, float* __restrict__ x0, int N)
{
    __shared__ float Wc[KDIM * FDIM];
    __shared__ float W1s[FDIM * FDIM];
    __shared__ float W2s[FDIM * FDIM];
    __shared__ float emb_s[MAXZ * FDIM];
    int tid = threadIdx.x;
    for (int i = tid; i < KDIM * FDIM; i += 256)
        Wc[i] = 0.282095f * Wr1_0[i] + Wr2_0[i];
    for (int i = tid; i < FDIM * FDIM; i += 256) { W1s[i] = W1_0[i]; W2s[i] = W2_0[i]; }
    for (int i = tid; i < MAXZ * FDIM; i += 256) emb_s[i] = embed[i];
    __syncthreads();

    int a = (blockIdx.x * 256 + tid) >> 6;   // wave per atom
    if (a >= N) return;
    int lane = tid & 63;
    int j = lane >> 5, f = lane & 31;
    int deg = min(counts[a], BINCAP);
    const int4* row = bins + a * BINCAP;
    float acc = 0.f;
    for (int i = j; i < deg; i += 2) {       // two records in flight per wave
        int4 R = row[i];
        int zs = R.x >> 14;
        float cut = __int_as_float(R.z);
        float tt  = __int_as_float(R.w);
        float T0 = 1.0f, T1 = tt;
        float gc = Wc[f] + Wc[FDIM + f] * tt;
        #pragma unroll
        for (int k = 2; k < KDIM; ++k) {
            float T2 = 2.0f * tt * T1 - T0;
            gc = fmaf(Wc[k * FDIM + f], T2, gc);
            T0 = T1; T1 = T2;
        }
        acc = fmaf(cut * gc, emb_s[zs * FDIM + f], acc);
    }
    acc += __shfl_down(acc, 32);             // merge the two half-waves
    // fused MLP1 (valid on lanes<32; upper lanes compute garbage, unused)
    float h = 0.f;
    #pragma unroll
    for (int g = 0; g < FDIM; ++g)
        h = fmaf(__shfl(acc, g, 32), W1s[g * FDIM + f], h);
    float cc = h * h / (1.0f + __expf(-h));  // h * silu(h)
    float xo = acc;
    #pragma unroll
    for (int g = 0; g < FDIM; ++g)
        xo = fmaf(__shfl(cc, g, 32), W2s[g * FDIM + f], xo);
    if (lane < 32) x0[a * FDIM + f] = xo;
}

// ---- K3: gather layer-1 + fused MLP2 + output reduction ----
__global__ __launch_bounds__(256) void gather2_k(
    const int* __restrict__ counts, const int4* __restrict__ bins,
    const float* __restrict__ x0, const float* __restrict__ pair,
    const float* __restrict__ Wr1_1, const float* __restrict__ W1_1,
    const float* __restrict__ W2_1, const float* __restrict__ w_out,
    const float* __restrict__ b_out, const int* __restrict__ Z,
    const int* __restrict__ bseg, const float* __restrict__ bmask,
    const float* __restrict__ amask, float* __restrict__ out, int N)
{
    __shared__ float Wg[KDIM * FDIM];
    __shared__ float W1s[FDIM * FDIM];
    __shared__ float W2s[FDIM * FDIM];
    __shared__ float wo[FDIM];
    int tid = threadIdx.x;
    for (int i = tid; i < KDIM * FDIM; i += 256) Wg[i] = Wr1_1[i];
    for (int i = tid; i < FDIM * FDIM; i += 256) { W1s[i] = W1_1[i]; W2s[i] = W2_1[i]; }
    if (tid < FDIM) wo[tid] = w_out[tid];
    __syncthreads();

    int a = (blockIdx.x * 256 + tid) >> 6;   // wave per atom
    if (a >= N) return;
    int lane = tid & 63;
    int j = lane >> 5, f = lane & 31;
    int deg = min(counts[a], BINCAP);
    const int4* row = bins + a * BINCAP;
    float acc = 0.f;
    for (int i = j; i < deg; i += 2) {
        int4 R = row[i];
        int s = R.x & 0x3FFF;
        float cut = __int_as_float(R.z);
        float tt  = __int_as_float(R.w);
        float T0 = 1.0f, T1 = tt;
        float gr = Wg[f] + Wg[FDIM + f] * tt;
        #pragma unroll
        for (int k = 2; k < KDIM; ++k) {
            float T2 = 2.0f * tt * T1 - T0;
            gr = fmaf(Wg[k * FDIM + f], T2, gr);
            T0 = T1; T1 = T2;
        }
        acc = fmaf(cut * gr, x0[s * FDIM + f], acc);
    }
    acc += __shfl_down(acc, 32);
    float h = 0.f;
    #pragma unroll
    for (int g = 0; g < FDIM; ++g)
        h = fmaf(__shfl(acc, g, 32), W1s[g * FDIM + f], h);
    float cc = h / (1.0f + __expf(-h));      // silu
    float xo = acc;
    #pragma unroll
    for (int g = 0; g < FDIM; ++g)
        xo = fmaf(__shfl(cc, g, 32), W2s[g * FDIM + f], xo);
    float ea = xo * wo[f];
    #pragma unroll
    for (int m = 16; m >= 1; m >>= 1) ea += __shfl_xor(ea, m, 32);
    if (lane == 0) {
        float e_atom = ea + b_out[Z[a]] + pair[a];
        int b = bseg[a];
        atomicAdd(&out[b], e_atom * amask[a] * bmask[b]);
    }
}

extern "C" void kernel_launch(void* const* d_in, const int* in_sizes, int n_in,
                              void* d_out, int out_size, void* d_ws, size_t ws_size,
                              hipStream_t stream) {
    int N = in_sizes[0];
    int E = in_sizes[2];
    int B = in_sizes[6];

    const int*   Z      = (const int*)d_in[0];
    const float* pos    = (const float*)d_in[1];
    const int*   dst    = (const int*)d_in[2];
    const int*   src    = (const int*)d_in[3];
    const int*   bseg   = (const int*)d_in[4];
    const float* bmask  = (const float*)d_in[6];
    const float* amask  = (const float*)d_in[7];
    const float* embed  = (const float*)d_in[8];
    const float* Wr1_0  = (const float*)d_in[9];
    const float* Wr2_0  = (const float*)d_in[10];
    const float* W1_0   = (const float*)d_in[11];
    const float* W2_0   = (const float*)d_in[12];
    const float* Wr1_1  = (const float*)d_in[13];
    const float* W1_1   = (const float*)d_in[14];
    const float* W2_1   = (const float*)d_in[15];
    const float* w_out  = (const float*)d_in[16];
    const float* b_out  = (const float*)d_in[17];
    float* out = (float*)d_out;

    // ws layout: [bins N*48*16B][counts N][pair N][x0 N*32]
    int4*  bins   = (int4*)d_ws;
    int*   counts = (int*)(bins + (size_t)N * BINCAP);
    float* pair   = (float*)(counts + N);
    float* x0     = pair + N;

    hipMemsetAsync(counts, 0, (size_t)2 * N * sizeof(int), stream);  // counts+pair
    hipMemsetAsync(out, 0, (size_t)B * sizeof(float), stream);

    int eb = (E / 4 + 255) / 256;
    edge_k<<<eb, 256, 0, stream>>>(dst, src, Z, pos, counts, pair, bins, E);

    int gb = (N * 64 + 255) / 256;   // wave per atom
    gather1_k<<<gb, 256, 0, stream>>>(counts, bins, embed, Wr1_0, Wr2_0,
                                      W1_0, W2_0, x0, N);
    gather2_k<<<gb, 256, 0, stream>>>(counts, bins, x0, pair, Wr1_1, W1_1, W2_1,
                                      w_out, b_out, Z, bseg, bmask, amask, out, N);
}